// Round 1
// baseline (4860.739 us; speedup 1.0000x reference)
//
#include <hip/hip_runtime.h>
#include <hip/hip_bf16.h>
#include <math.h>

// Qwen3.5 attention block, fp32 correctness-first baseline.
// Pipeline: gemm128(QKV) -> norm_rope_gate (in-place) -> flash_attn -> gemm128(out).

namespace {
constexpr int kT   = 4096;
constexpr int kHid = 2048;
constexpr int kH   = 16;
constexpr int kHkv = 2;
constexpr int kD   = 128;
constexpr int kNqkv = (2 * kH + 2 * kHkv) * kD;  // 4608
constexpr int kQsz  = 2 * kH * kD;               // 4096
constexpr float kEps = 1e-6f;
constexpr float kScale = 0.08838834764831845f;   // 128^-0.5
}

// C[M,N] = A[M,K] @ B[K,N], fp32, 128x128 tile, BK=16, 256 thr, 8x8 micro.
__global__ __launch_bounds__(256)
void gemm128(const float* __restrict__ A, const float* __restrict__ B,
             float* __restrict__ C, int M, int N, int K) {
  __shared__ float As[16][129];  // [k][m] (transposed stage)
  __shared__ float Bs[16][129];  // [k][n]
  const int tid = threadIdx.x;
  const int tx = tid & 15, ty = tid >> 4;
  const long bm = (long)blockIdx.x * 128, bn = (long)blockIdx.y * 128;
  float acc[8][8];
#pragma unroll
  for (int a = 0; a < 8; ++a)
#pragma unroll
    for (int b = 0; b < 8; ++b) acc[a][b] = 0.f;

  for (int k0 = 0; k0 < K; k0 += 16) {
#pragma unroll
    for (int it = 0; it < 2; ++it) {
      int idx = it * 256 + tid;
      int row = idx >> 2, kc = (idx & 3) << 2;                 // A: 128 rows x 16 k
      float4 a4 = *(const float4*)(A + (bm + row) * (long)K + k0 + kc);
      As[kc + 0][row] = a4.x; As[kc + 1][row] = a4.y;
      As[kc + 2][row] = a4.z; As[kc + 3][row] = a4.w;
      int brow = idx >> 5, bc = (idx & 31) << 2;               // B: 16 rows x 128 n
      float4 b4 = *(const float4*)(B + (long)(k0 + brow) * N + bn + bc);
      Bs[brow][bc + 0] = b4.x; Bs[brow][bc + 1] = b4.y;
      Bs[brow][bc + 2] = b4.z; Bs[brow][bc + 3] = b4.w;
    }
    __syncthreads();
#pragma unroll
    for (int k = 0; k < 16; ++k) {
      float ar[8], br[8];
#pragma unroll
      for (int a = 0; a < 8; ++a) ar[a] = As[k][ty + 16 * a];  // broadcast across tx
#pragma unroll
      for (int b = 0; b < 8; ++b) br[b] = Bs[k][tx + 16 * b];  // conflict-free across tx
#pragma unroll
      for (int a = 0; a < 8; ++a)
#pragma unroll
        for (int b = 0; b < 8; ++b) acc[a][b] = fmaf(ar[a], br[b], acc[a][b]);
    }
    __syncthreads();
  }
#pragma unroll
  for (int a = 0; a < 8; ++a)
#pragma unroll
    for (int b = 0; b < 8; ++b)
      C[(bm + ty + 16 * a) * (long)N + bn + tx + 16 * b] = acc[a][b];  // coalesced in tx
}

// One block per (t, head). h < kH: q head (RMSNorm+RoPE, sigmoid on gate slot).
// h >= kH: k head (RMSNorm+RoPE). All in place in the qkv buffer.
__global__ __launch_bounds__(128)
void norm_rope_gate(float* __restrict__ qkv, const float* __restrict__ cosb,
                    const float* __restrict__ sinb, const float* __restrict__ qw,
                    const float* __restrict__ kw) {
  const int blk = blockIdx.x;
  const int t = blk / (kH + kHkv);
  const int h = blk % (kH + kHkv);
  const int i = threadIdx.x;
  const bool isq = (h < kH);
  const long base = (long)t * kNqkv + (isq ? h * 2 * kD : kQsz + (h - kH) * kD);
  float x = qkv[base + i];
  float v = x * x;
#pragma unroll
  for (int off = 1; off < 64; off <<= 1) v += __shfl_xor(v, off, 64);
  __shared__ float wsum[2];
  if ((i & 63) == 0) wsum[i >> 6] = v;
  __syncthreads();
  float rms = rsqrtf((wsum[0] + wsum[1]) * (1.0f / kD) + kEps);
  float n = x * rms * (isq ? qw[i] : kw[i]);
  __shared__ float nb[128];
  nb[i] = n;
  __syncthreads();
  float rot = (i < 64) ? -nb[i + 64] : nb[i - 64];
  qkv[base + i] = n * cosb[t * kD + i] + rot * sinb[t * kD + i];
  if (isq) {  // gate -> sigmoid(gate), stored in place
    float g = qkv[base + kD + i];
    qkv[base + kD + i] = 1.0f / (1.0f + __expf(-g));
  }
}

// Flash attention, causal, GQA (rep=8). Grid (T/64, H), 256 threads.
// BM=64 q rows, BN=32 k rows/tile; K and V share one LDS buffer (58KB total).
__global__ __launch_bounds__(256)
void flash_attn(const float* __restrict__ qkv, float* __restrict__ og) {
  __shared__ float Qs[64][129];
  __shared__ float KVs[32][129];
  __shared__ float Ps[64][33];
  const int tid = threadIdx.x;
  const int tx = tid & 15, ty = tid >> 4;
  const int bm = blockIdx.x;
  const int h = blockIdx.y;
  const int hk = h >> 3;          // h / (H/HKV)
  const int q0 = bm * 64;

#pragma unroll
  for (int it = 0; it < 8; ++it) {  // Q tile: 64 rows x 128 d
    int idx = it * 256 + tid;
    int row = idx >> 5, c = (idx & 31) << 2;
    float4 q4 = *(const float4*)(qkv + (long)(q0 + row) * kNqkv + h * 2 * kD + c);
    Qs[row][c] = q4.x; Qs[row][c + 1] = q4.y; Qs[row][c + 2] = q4.z; Qs[row][c + 3] = q4.w;
  }
  float m_i[4], l_i[4], O[4][8];
#pragma unroll
  for (int a = 0; a < 4; ++a) {
    m_i[a] = -1e30f; l_i[a] = 0.f;
#pragma unroll
    for (int b = 0; b < 8; ++b) O[a][b] = 0.f;
  }

  const int kn_end = 2 * bm + 1;
  for (int kn = 0; kn <= kn_end; ++kn) {
    __syncthreads();  // prior iteration done with KVs/Ps
#pragma unroll
    for (int it = 0; it < 4; ++it) {  // K tile: 32 rows x 128 d
      int idx = it * 256 + tid;
      int row = idx >> 5, c = (idx & 31) << 2;
      float4 k4 = *(const float4*)(qkv + (long)(kn * 32 + row) * kNqkv + kQsz + hk * kD + c);
      KVs[row][c] = k4.x; KVs[row][c + 1] = k4.y; KVs[row][c + 2] = k4.z; KVs[row][c + 3] = k4.w;
    }
    __syncthreads();

    float s[4][2] = {{0.f, 0.f}, {0.f, 0.f}, {0.f, 0.f}, {0.f, 0.f}};
#pragma unroll 4
    for (int d = 0; d < kD; ++d) {
      float qa[4], kb[2];
#pragma unroll
      for (int a = 0; a < 4; ++a) qa[a] = Qs[ty + 16 * a][d];
#pragma unroll
      for (int b = 0; b < 2; ++b) kb[b] = KVs[tx + 16 * b][d];
#pragma unroll
      for (int a = 0; a < 4; ++a)
#pragma unroll
        for (int b = 0; b < 2; ++b) s[a][b] = fmaf(qa[a], kb[b], s[a][b]);
    }
    const bool needmask = (kn >= 2 * bm);
#pragma unroll
    for (int a = 0; a < 4; ++a) {
      int i = q0 + ty + 16 * a;
#pragma unroll
      for (int b = 0; b < 2; ++b) {
        s[a][b] *= kScale;
        int j = kn * 32 + tx + 16 * b;
        if (needmask && j > i) s[a][b] = -1e30f;
      }
    }
    // online softmax (row owned by the 16 consecutive lanes sharing ty)
#pragma unroll
    for (int a = 0; a < 4; ++a) {
      float mx = fmaxf(s[a][0], s[a][1]);
#pragma unroll
      for (int off = 1; off < 16; off <<= 1) mx = fmaxf(mx, __shfl_xor(mx, off, 64));
      float mnew = fmaxf(m_i[a], mx);
      float p0 = __expf(s[a][0] - mnew);
      float p1 = __expf(s[a][1] - mnew);
      float sum = p0 + p1;
#pragma unroll
      for (int off = 1; off < 16; off <<= 1) sum += __shfl_xor(sum, off, 64);
      float alpha = __expf(m_i[a] - mnew);
      l_i[a] = l_i[a] * alpha + sum;
      m_i[a] = mnew;
#pragma unroll
      for (int b = 0; b < 8; ++b) O[a][b] *= alpha;
      Ps[ty + 16 * a][tx] = p0;
      Ps[ty + 16 * a][tx + 16] = p1;
    }
    __syncthreads();  // everyone done reading K from KVs
#pragma unroll
    for (int it = 0; it < 4; ++it) {  // V tile overwrites KVs
      int idx = it * 256 + tid;
      int row = idx >> 5, c = (idx & 31) << 2;
      float4 v4 = *(const float4*)(qkv + (long)(kn * 32 + row) * kNqkv + kQsz + kHkv * kD + hk * kD + c);
      KVs[row][c] = v4.x; KVs[row][c + 1] = v4.y; KVs[row][c + 2] = v4.z; KVs[row][c + 3] = v4.w;
    }
    __syncthreads();
#pragma unroll 4
    for (int n = 0; n < 32; ++n) {  // O += P @ V
      float pa[4], vb[8];
#pragma unroll
      for (int a = 0; a < 4; ++a) pa[a] = Ps[ty + 16 * a][n];
#pragma unroll
      for (int b = 0; b < 8; ++b) vb[b] = KVs[n][tx + 16 * b];
#pragma unroll
      for (int a = 0; a < 4; ++a)
#pragma unroll
        for (int b = 0; b < 8; ++b) O[a][b] = fmaf(pa[a], vb[b], O[a][b]);
    }
  }
  // epilogue: normalize, apply sigmoid(gate) (already stored in gate slot)
#pragma unroll
  for (int a = 0; a < 4; ++a) {
    int t = q0 + ty + 16 * a;
    float inv = 1.0f / l_i[a];
#pragma unroll
    for (int b = 0; b < 8; ++b) {
      int d = tx + 16 * b;
      float g = qkv[(long)t * kNqkv + h * 2 * kD + kD + d];
      og[(long)t * kHid + h * kD + d] = O[a][b] * inv * g;
    }
  }
}

extern "C" void kernel_launch(void* const* d_in, const int* in_sizes, int n_in,
                              void* d_out, int out_size, void* d_ws, size_t ws_size,
                              hipStream_t stream) {
  (void)in_sizes; (void)n_in; (void)out_size; (void)ws_size;
  const float* hs   = (const float*)d_in[0];
  const float* cosb = (const float*)d_in[1];
  const float* sinb = (const float*)d_in[2];
  const float* wqkv = (const float*)d_in[3];
  const float* wo   = (const float*)d_in[4];
  const float* qw   = (const float*)d_in[5];
  const float* kw   = (const float*)d_in[6];
  float* out = (float*)d_out;

  float* qkv = (float*)d_ws;                  // T x 4608 fp32 (75.5 MB)
  float* og  = qkv + (long)kT * kNqkv;        // T x 2048 fp32 (33.5 MB)

  gemm128<<<dim3(kT / 128, kNqkv / 128), 256, 0, stream>>>(hs, wqkv, qkv, kT, kNqkv, kHid);
  norm_rope_gate<<<dim3(kT * (kH + kHkv)), 128, 0, stream>>>(qkv, cosb, sinb, qw, kw);
  flash_attn<<<dim3(kT / 64, kH), 256, 0, stream>>>(qkv, og);
  gemm128<<<dim3(kT / 128, kHid / 128), 256, 0, stream>>>(og, wo, out, kT, kHid, kHid);
}

// Round 2
// 2114.984 us; speedup vs baseline: 2.2982x; 2.2982x over previous
//
#include <hip/hip_runtime.h>
#include <hip/hip_bf16.h>
#include <math.h>

// Qwen3.5 attention block.
// gemm128(QKV, fp32) -> norm_rope_cvt (bf16 Q/K/V packed in-place) ->
// flash_attn_mfma (bf16 MFMA) -> gemm128(out, fp32).

namespace {
constexpr int kT   = 4096;
constexpr int kHid = 2048;
constexpr int kH   = 16;
constexpr int kHkv = 2;
constexpr int kD   = 128;
constexpr int kNqkv = (2 * kH + 2 * kHkv) * kD;  // 4608 floats per row
constexpr int kQsz  = 2 * kH * kD;               // 4096
constexpr int kRowU = kNqkv * 2;                 // 9216 ushorts per row
constexpr float kEps = 1e-6f;
constexpr float kScale = 0.08838834764831845f;   // 128^-0.5
}

typedef __attribute__((ext_vector_type(8))) short short8;
typedef __attribute__((ext_vector_type(4))) float floatx4;

__device__ inline unsigned short f2bf(float x) {
  unsigned u = __float_as_uint(x);
  u = (u + 0x7fffu + ((u >> 16) & 1u)) >> 16;
  return (unsigned short)u;
}

__device__ inline void gload_lds16(const void* g, void* l) {
  typedef const __attribute__((address_space(1))) unsigned GQ;
  typedef __attribute__((address_space(3))) unsigned LQ;
  __builtin_amdgcn_global_load_lds((GQ*)g, (LQ*)l, 16, 0, 0);
}

// ---------------- fp32 GEMM (unchanged from round 1) ----------------
__global__ __launch_bounds__(256)
void gemm128(const float* __restrict__ A, const float* __restrict__ B,
             float* __restrict__ C, int M, int N, int K) {
  __shared__ float As[16][129];
  __shared__ float Bs[16][129];
  const int tid = threadIdx.x;
  const int tx = tid & 15, ty = tid >> 4;
  const long bm = (long)blockIdx.x * 128, bn = (long)blockIdx.y * 128;
  float acc[8][8];
#pragma unroll
  for (int a = 0; a < 8; ++a)
#pragma unroll
    for (int b = 0; b < 8; ++b) acc[a][b] = 0.f;

  for (int k0 = 0; k0 < K; k0 += 16) {
#pragma unroll
    for (int it = 0; it < 2; ++it) {
      int idx = it * 256 + tid;
      int row = idx >> 2, kc = (idx & 3) << 2;
      float4 a4 = *(const float4*)(A + (bm + row) * (long)K + k0 + kc);
      As[kc + 0][row] = a4.x; As[kc + 1][row] = a4.y;
      As[kc + 2][row] = a4.z; As[kc + 3][row] = a4.w;
      int brow = idx >> 5, bc = (idx & 31) << 2;
      float4 b4 = *(const float4*)(B + (long)(k0 + brow) * N + bn + bc);
      Bs[brow][bc + 0] = b4.x; Bs[brow][bc + 1] = b4.y;
      Bs[brow][bc + 2] = b4.z; Bs[brow][bc + 3] = b4.w;
    }
    __syncthreads();
#pragma unroll
    for (int k = 0; k < 16; ++k) {
      float ar[8], br[8];
#pragma unroll
      for (int a = 0; a < 8; ++a) ar[a] = As[k][ty + 16 * a];
#pragma unroll
      for (int b = 0; b < 8; ++b) br[b] = Bs[k][tx + 16 * b];
#pragma unroll
      for (int a = 0; a < 8; ++a)
#pragma unroll
        for (int b = 0; b < 8; ++b) acc[a][b] = fmaf(ar[a], br[b], acc[a][b]);
    }
    __syncthreads();
  }
#pragma unroll
  for (int a = 0; a < 8; ++a)
#pragma unroll
    for (int b = 0; b < 8; ++b)
      C[(bm + ty + 16 * a) * (long)N + bn + tx + 16 * b] = acc[a][b];
}

// ------------- RMSNorm + RoPE + bf16 pack (in place) -------------
// Grid: T*20 blocks of 128. h<16: q head; 16..17: k head; 18..19: v convert.
// bf16 values are packed into the LOWER HALF of each head's fp32 slot.
__global__ __launch_bounds__(128)
void norm_rope_cvt(float* qkv, const float* __restrict__ cosb,
                   const float* __restrict__ sinb, const float* __restrict__ qw,
                   const float* __restrict__ kw) {
  unsigned short* qkvu = (unsigned short*)qkv;
  const int blk = blockIdx.x;
  const int t = blk / 20;
  const int h = blk % 20;
  const int i = threadIdx.x;

  if (h >= 18) {  // v heads: bf16 convert only
    int hv = h - 18;
    long fbase = (long)t * kNqkv + kQsz + kHkv * kD + hv * kD;
    float x = qkv[fbase + i];
    __syncthreads();  // all reads before in-place overwrite
    qkvu[(long)t * kRowU + 8704 + 256 * hv + i] = f2bf(x);
    return;
  }
  const bool isq = (h < kH);
  const long base = (long)t * kNqkv + (isq ? h * 2 * kD : kQsz + (h - kH) * kD);
  float x = qkv[base + i];
  float v = x * x;
#pragma unroll
  for (int off = 1; off < 64; off <<= 1) v += __shfl_xor(v, off, 64);
  __shared__ float wsum[2];
  if ((i & 63) == 0) wsum[i >> 6] = v;
  __syncthreads();
  float rms = rsqrtf((wsum[0] + wsum[1]) * (1.0f / kD) + kEps);
  float nv = x * rms * (isq ? qw[i] : kw[i]);
  __shared__ float nb[128];
  nb[i] = nv;
  __syncthreads();  // also guarantees every thread's x-read is done
  float rot = (i < 64) ? -nb[i + 64] : nb[i - 64];
  float ro = nv * cosb[t * kD + i] + rot * sinb[t * kD + i];
  if (isq) {
    float g = qkv[base + kD + i];
    qkv[base + kD + i] = 1.0f / (1.0f + __expf(-g));     // sigmoid in place (fp32)
    qkvu[(long)t * kRowU + 512 * h + i] = f2bf(ro);      // bf16 q
  } else {
    qkvu[(long)t * kRowU + 8192 + 256 * (h - kH) + i] = f2bf(ro);  // bf16 k
  }
}

// ---------------- bf16 MFMA flash attention ----------------
// Grid (T/64, H), 256 thr (4 waves). Wave w owns q rows q0+16w..+15.
// mfma_f32_16x16x32_bf16 layouts: A[m=lane&15][k=quad*8+j],
// B[n=lane&15][k=quad*8+j], C/D col=lane&15 row=quad*4+reg.
__global__ __launch_bounds__(256)
void flash_attn_mfma(const unsigned short* qkvu, const float* qkvf,
                     float* __restrict__ og) {
  __shared__ __align__(16) unsigned short Ks[64 * 128];  // XOR-swizzled chunks
  __shared__ __align__(16) unsigned short Vs[64 * 128];  // row-major; later Ps[64][72]
  __shared__ __align__(16) unsigned short Vt[128 * 72];  // V transposed [d][key]

  const int tid = threadIdx.x;
  const int lane = tid & 63;
  const int w = tid >> 6;
  const int n = lane & 15;
  const int quad = lane >> 4;
  const int h = blockIdx.y;
  const int hk = h >> 3;
  const int bm = gridDim.x - 1 - blockIdx.x;  // big (late) tiles dispatched first
  const int q0 = bm * 64;

  // Q fragments, kept in registers for all KV tiles
  short8 qf[4];
  {
    const unsigned short* qrow = qkvu + (long)(q0 + 16 * w + n) * kRowU + 512 * h;
#pragma unroll
    for (int ks = 0; ks < 4; ++ks)
      qf[ks] = *(const short8*)(qrow + 32 * ks + 8 * quad);
  }

  floatx4 O[8];
  floatx4 zero = {0.f, 0.f, 0.f, 0.f};
#pragma unroll
  for (int dt = 0; dt < 8; ++dt) O[dt] = zero;
  float m_i[4], l_i[4];
#pragma unroll
  for (int r = 0; r < 4; ++r) { m_i[r] = -1e30f; l_i[r] = 0.f; }

  for (int kn = 0; kn <= bm; ++kn) {
    __syncthreads();  // A: prev tile fully consumed (Ks, Ps=Vs, Vt)
    // ---- stage K (swizzled) and V (straight) via global_load_lds ----
#pragma unroll
    for (int it = 0; it < 4; ++it) {
      int pc = (w * 4 + it) * 64 + lane;  // 16B chunk id, 0..1023
      int r = pc >> 4, c = pc & 15;
      int lc = c ^ (r & 15);
      const unsigned short* gk =
          qkvu + (long)(kn * 64 + r) * kRowU + 8192 + 256 * hk + 8 * lc;
      gload_lds16(gk, Ks + (w * 4 + it) * 512);
      const unsigned short* gv =
          qkvu + (long)(kn * 64 + r) * kRowU + 8704 + 256 * hk + 8 * c;
      gload_lds16(gv, Vs + (w * 4 + it) * 512);
    }
    __syncthreads();  // B: staging complete (drains vmcnt)

    // ---- S = Q K^T ----
    floatx4 S[4];
#pragma unroll
    for (int ct = 0; ct < 4; ++ct) S[ct] = zero;
#pragma unroll
    for (int ks = 0; ks < 4; ++ks) {
#pragma unroll
      for (int ct = 0; ct < 4; ++ct) {
        int row = 16 * ct + n;
        short8 kf = *(const short8*)(Ks + row * 128 + (((4 * ks + quad) ^ n) * 8));
        S[ct] = __builtin_amdgcn_mfma_f32_16x16x32_bf16(qf[ks], kf, S[ct], 0, 0, 0);
      }
    }

    // ---- transpose Vs[key][d] -> Vt[d][key] ----
    {
      int d0 = tid & 31, k8 = tid >> 5;
#pragma unroll
      for (int p = 0; p < 4; ++p) {
        int d = p * 32 + d0;
        union { short8 v; unsigned short u[8]; } pk;
#pragma unroll
        for (int i = 0; i < 8; ++i) pk.u[i] = Vs[(k8 * 8 + i) * 128 + d];
        *(short8*)(Vt + d * 72 + k8 * 8) = pk.v;
      }
    }
    __syncthreads();  // C: transpose reads of Vs done; Vt complete

    // ---- online softmax; write P (bf16) into Ps (aliases Vs) ----
    unsigned short* Ps = Vs;
    const bool diag = (kn == bm);
#pragma unroll
    for (int r = 0; r < 4; ++r) {
      float s0 = S[0][r] * kScale, s1 = S[1][r] * kScale;
      float s2 = S[2][r] * kScale, s3 = S[3][r] * kScale;
      if (diag) {
        int iloc = 16 * w + quad * 4 + r;
        if (n > iloc) s0 = -1e30f;
        if (16 + n > iloc) s1 = -1e30f;
        if (32 + n > iloc) s2 = -1e30f;
        if (48 + n > iloc) s3 = -1e30f;
      }
      float mx = fmaxf(fmaxf(s0, s1), fmaxf(s2, s3));
#pragma unroll
      for (int off = 8; off >= 1; off >>= 1) mx = fmaxf(mx, __shfl_xor(mx, off, 64));
      float mnew = fmaxf(m_i[r], mx);
      float p0 = __expf(s0 - mnew), p1 = __expf(s1 - mnew);
      float p2 = __expf(s2 - mnew), p3 = __expf(s3 - mnew);
      float sum = p0 + p1 + p2 + p3;
#pragma unroll
      for (int off = 8; off >= 1; off >>= 1) sum += __shfl_xor(sum, off, 64);
      float alpha = __expf(m_i[r] - mnew);
      m_i[r] = mnew;
      l_i[r] = l_i[r] * alpha + sum;
#pragma unroll
      for (int dt = 0; dt < 8; ++dt) O[dt][r] *= alpha;
      int prow = 16 * w + quad * 4 + r;
      Ps[prow * 72 + n] = f2bf(p0);
      Ps[prow * 72 + 16 + n] = f2bf(p1);
      Ps[prow * 72 + 32 + n] = f2bf(p2);
      Ps[prow * 72 + 48 + n] = f2bf(p3);
    }

    // ---- O += P V ---- (A-frag: own wave's Ps rows; B-frag: Vt)
#pragma unroll
    for (int ks = 0; ks < 2; ++ks) {
      short8 pf = *(const short8*)(Ps + (16 * w + n) * 72 + 32 * ks + 8 * quad);
#pragma unroll
      for (int dt = 0; dt < 8; ++dt) {
        short8 vf = *(const short8*)(Vt + (16 * dt + n) * 72 + 32 * ks + 8 * quad);
        O[dt] = __builtin_amdgcn_mfma_f32_16x16x32_bf16(pf, vf, O[dt], 0, 0, 0);
      }
    }
  }

  // ---- epilogue: normalize, gate, store ----
#pragma unroll
  for (int r = 0; r < 4; ++r) {
    int row = q0 + 16 * w + quad * 4 + r;
    float inv = 1.0f / l_i[r];
#pragma unroll
    for (int dt = 0; dt < 8; ++dt) {
      int col = 16 * dt + n;
      float g = qkvf[(long)row * kNqkv + 256 * h + 128 + col];
      og[(long)row * kHid + 128 * h + col] = O[dt][r] * inv * g;
    }
  }
}

extern "C" void kernel_launch(void* const* d_in, const int* in_sizes, int n_in,
                              void* d_out, int out_size, void* d_ws, size_t ws_size,
                              hipStream_t stream) {
  (void)in_sizes; (void)n_in; (void)out_size; (void)ws_size;
  const float* hs   = (const float*)d_in[0];
  const float* cosb = (const float*)d_in[1];
  const float* sinb = (const float*)d_in[2];
  const float* wqkv = (const float*)d_in[3];
  const float* wo   = (const float*)d_in[4];
  const float* qw   = (const float*)d_in[5];
  const float* kw   = (const float*)d_in[6];
  float* out = (float*)d_out;

  float* qkv = (float*)d_ws;                 // T x 4608 fp32 (75.5 MB)
  float* og  = qkv + (long)kT * kNqkv;       // T x 2048 fp32 (33.5 MB)

  gemm128<<<dim3(kT / 128, kNqkv / 128), 256, 0, stream>>>(hs, wqkv, qkv, kT, kNqkv, kHid);
  norm_rope_cvt<<<dim3(kT * 20), 128, 0, stream>>>(qkv, cosb, sinb, qw, kw);
  flash_attn_mfma<<<dim3(kT / 64, kH), 256, 0, stream>>>((const unsigned short*)qkv, qkv, og);
  gemm128<<<dim3(kT / 128, kHid / 128), 256, 0, stream>>>(og, wo, out, kT, kHid, kHid);
}

// Round 3
// 733.408 us; speedup vs baseline: 6.6276x; 2.8838x over previous
//
#include <hip/hip_runtime.h>
#include <hip/hip_bf16.h>
#include <math.h>

// Qwen3.5 attention block, bf16-MFMA everywhere.
// cvt(hs->bf16), transpose_cvt(w_qkv) -> gemm_bf16(QKV) -> norm_rope_cvt ->
// transpose_cvt(w_o) -> flash_attn_mfma (og bf16) -> gemm_bf16(out).

namespace {
constexpr int kT   = 4096;
constexpr int kHid = 2048;
constexpr int kH   = 16;
constexpr int kHkv = 2;
constexpr int kD   = 128;
constexpr int kNqkv = (2 * kH + 2 * kHkv) * kD;  // 4608 floats per row
constexpr int kQsz  = 2 * kH * kD;               // 4096
constexpr int kRowU = kNqkv * 2;                 // 9216 ushorts per row
constexpr float kEps = 1e-6f;
constexpr float kScale = 0.08838834764831845f;   // 128^-0.5
}

typedef __attribute__((ext_vector_type(8))) short short8;
typedef __attribute__((ext_vector_type(4))) float floatx4;

__device__ inline unsigned short f2bf(float x) {
  unsigned u = __float_as_uint(x);
  u = (u + 0x7fffu + ((u >> 16) & 1u)) >> 16;
  return (unsigned short)u;
}

__device__ inline void gload_lds16(const void* g, void* l) {
  typedef const __attribute__((address_space(1))) unsigned GQ;
  typedef __attribute__((address_space(3))) unsigned LQ;
  __builtin_amdgcn_global_load_lds((GQ*)g, (LQ*)l, 16, 0, 0);
}

// ---- fp32 -> bf16 elementwise (4 elems/thread) ----
__global__ __launch_bounds__(256)
void cvt_bf16(const float* __restrict__ in, unsigned short* __restrict__ out,
              long nelem) {
  long i = ((long)blockIdx.x * 256 + threadIdx.x) * 4;
  if (i >= nelem) return;
  float4 v = *(const float4*)(in + i);
  unsigned long long p = (unsigned long long)f2bf(v.x) |
                         ((unsigned long long)f2bf(v.y) << 16) |
                         ((unsigned long long)f2bf(v.z) << 32) |
                         ((unsigned long long)f2bf(v.w) << 48);
  *(unsigned long long*)(out + i) = p;
}

// ---- fp32 [R][C] -> bf16 [C][R] tiled transpose ----
__global__ __launch_bounds__(256)
void transpose_cvt(const float* __restrict__ in, unsigned short* __restrict__ out,
                   int R, int C) {
  __shared__ float t[32][33];
  const int bx = blockIdx.x * 32;  // column tile
  const int by = blockIdx.y * 32;  // row tile
  const int x = threadIdx.x & 31, y = threadIdx.x >> 5;  // y: 0..7
#pragma unroll
  for (int j = 0; j < 4; ++j)
    t[y * 4 + j][x] = in[(long)(by + y * 4 + j) * C + bx + x];
  __syncthreads();
#pragma unroll
  for (int j = 0; j < 4; ++j)
    out[(long)(bx + y * 4 + j) * R + by + x] = f2bf(t[x][y * 4 + j]);
}

// ---- C[M,N] fp32 = A[M,K]bf16 @ Bt[N,K]bf16^T. 128x128 tile, BK=32. ----
// 4 waves in 2x2; each wave 4x4 tiles of 16x16x32 MFMA. global_load_lds
// staging with XOR chunk swizzle (c ^ (r>>1)&3) -> frag reads 2-way (free).
__global__ __launch_bounds__(256)
void gemm_bf16(const unsigned short* __restrict__ A,
               const unsigned short* __restrict__ Bt, float* __restrict__ C,
               int M, int N, int K) {
  __shared__ __align__(16) unsigned short As[128 * 32];
  __shared__ __align__(16) unsigned short Bs[128 * 32];
  const int tid = threadIdx.x;
  const int lane = tid & 63;
  const int w = tid >> 6;
  const int wr = w >> 1, wc = w & 1;
  const int n = lane & 15;
  const int quad = lane >> 4;
  const long bm = (long)blockIdx.x * 128, bn = (long)blockIdx.y * 128;

  floatx4 acc[4][4];
  floatx4 zero = {0.f, 0.f, 0.f, 0.f};
#pragma unroll
  for (int a = 0; a < 4; ++a)
#pragma unroll
    for (int b = 0; b < 4; ++b) acc[a][b] = zero;

  for (int k0 = 0; k0 < K; k0 += 32) {
    __syncthreads();  // prev frag reads done before overwrite
#pragma unroll
    for (int it = 0; it < 2; ++it) {
      int ci = (w * 2 + it) * 64 + lane;     // LDS slot chunk id 0..511
      int r = ci >> 2, c = ci & 3;
      int cg = c ^ ((r >> 1) & 3);           // global chunk for this slot
      gload_lds16(A + (bm + r) * (long)K + k0 + cg * 8, As + (w * 2 + it) * 512);
      gload_lds16(Bt + (bn + r) * (long)K + k0 + cg * 8, Bs + (w * 2 + it) * 512);
    }
    __syncthreads();  // staging complete (drains vmcnt)

    short8 af[4], bf[4];
#pragma unroll
    for (int a = 0; a < 4; ++a) {
      int m = wr * 64 + a * 16 + n;
      af[a] = *(const short8*)(As + m * 32 + (quad ^ ((m >> 1) & 3)) * 8);
    }
#pragma unroll
    for (int b = 0; b < 4; ++b) {
      int nn = wc * 64 + b * 16 + n;
      bf[b] = *(const short8*)(Bs + nn * 32 + (quad ^ ((nn >> 1) & 3)) * 8);
    }
#pragma unroll
    for (int a = 0; a < 4; ++a)
#pragma unroll
      for (int b = 0; b < 4; ++b)
        acc[a][b] = __builtin_amdgcn_mfma_f32_16x16x32_bf16(af[a], bf[b], acc[a][b], 0, 0, 0);
  }
#pragma unroll
  for (int a = 0; a < 4; ++a)
#pragma unroll
    for (int b = 0; b < 4; ++b)
#pragma unroll
      for (int r = 0; r < 4; ++r)
        C[(bm + wr * 64 + a * 16 + quad * 4 + r) * (long)N + bn + wc * 64 + b * 16 + n] =
            acc[a][b][r];
}

// ------------- RMSNorm + RoPE + bf16 pack (in place) -------------
__global__ __launch_bounds__(128)
void norm_rope_cvt(float* qkv, const float* __restrict__ cosb,
                   const float* __restrict__ sinb, const float* __restrict__ qw,
                   const float* __restrict__ kw) {
  unsigned short* qkvu = (unsigned short*)qkv;
  const int blk = blockIdx.x;
  const int t = blk / 20;
  const int h = blk % 20;
  const int i = threadIdx.x;

  if (h >= 18) {  // v heads: bf16 convert only
    int hv = h - 18;
    long fbase = (long)t * kNqkv + kQsz + kHkv * kD + hv * kD;
    float x = qkv[fbase + i];
    __syncthreads();
    qkvu[(long)t * kRowU + 8704 + 256 * hv + i] = f2bf(x);
    return;
  }
  const bool isq = (h < kH);
  const long base = (long)t * kNqkv + (isq ? h * 2 * kD : kQsz + (h - kH) * kD);
  float x = qkv[base + i];
  float v = x * x;
#pragma unroll
  for (int off = 1; off < 64; off <<= 1) v += __shfl_xor(v, off, 64);
  __shared__ float wsum[2];
  if ((i & 63) == 0) wsum[i >> 6] = v;
  __syncthreads();
  float rms = rsqrtf((wsum[0] + wsum[1]) * (1.0f / kD) + kEps);
  float nv = x * rms * (isq ? qw[i] : kw[i]);
  __shared__ float nb[128];
  nb[i] = nv;
  __syncthreads();
  float rot = (i < 64) ? -nb[i + 64] : nb[i - 64];
  float ro = nv * cosb[t * kD + i] + rot * sinb[t * kD + i];
  if (isq) {
    float g = qkv[base + kD + i];
    qkv[base + kD + i] = 1.0f / (1.0f + __expf(-g));
    qkvu[(long)t * kRowU + 512 * h + i] = f2bf(ro);
  } else {
    qkvu[(long)t * kRowU + 8192 + 256 * (h - kH) + i] = f2bf(ro);
  }
}

// ---------------- bf16 MFMA flash attention ----------------
__global__ __launch_bounds__(256)
void flash_attn_mfma(const unsigned short* qkvu, const float* qkvf,
                     unsigned short* __restrict__ og) {
  __shared__ __align__(16) unsigned short Ks[64 * 128];
  __shared__ __align__(16) unsigned short Vs[64 * 128];  // later Ps[64][72]
  __shared__ __align__(16) unsigned short Vt[128 * 72];

  const int tid = threadIdx.x;
  const int lane = tid & 63;
  const int w = tid >> 6;
  const int n = lane & 15;
  const int quad = lane >> 4;
  const int h = blockIdx.y;
  const int hk = h >> 3;
  const int bm = gridDim.x - 1 - blockIdx.x;
  const int q0 = bm * 64;

  short8 qf[4];
  {
    const unsigned short* qrow = qkvu + (long)(q0 + 16 * w + n) * kRowU + 512 * h;
#pragma unroll
    for (int ks = 0; ks < 4; ++ks)
      qf[ks] = *(const short8*)(qrow + 32 * ks + 8 * quad);
  }

  floatx4 O[8];
  floatx4 zero = {0.f, 0.f, 0.f, 0.f};
#pragma unroll
  for (int dt = 0; dt < 8; ++dt) O[dt] = zero;
  float m_i[4], l_i[4];
#pragma unroll
  for (int r = 0; r < 4; ++r) { m_i[r] = -1e30f; l_i[r] = 0.f; }

  for (int kn = 0; kn <= bm; ++kn) {
    __syncthreads();
#pragma unroll
    for (int it = 0; it < 4; ++it) {
      int pc = (w * 4 + it) * 64 + lane;
      int r = pc >> 4, c = pc & 15;
      int lc = c ^ (r & 15);
      const unsigned short* gk =
          qkvu + (long)(kn * 64 + r) * kRowU + 8192 + 256 * hk + 8 * lc;
      gload_lds16(gk, Ks + (w * 4 + it) * 512);
      const unsigned short* gv =
          qkvu + (long)(kn * 64 + r) * kRowU + 8704 + 256 * hk + 8 * c;
      gload_lds16(gv, Vs + (w * 4 + it) * 512);
    }
    __syncthreads();

    floatx4 S[4];
#pragma unroll
    for (int ct = 0; ct < 4; ++ct) S[ct] = zero;
#pragma unroll
    for (int ks = 0; ks < 4; ++ks) {
#pragma unroll
      for (int ct = 0; ct < 4; ++ct) {
        int row = 16 * ct + n;
        short8 kf = *(const short8*)(Ks + row * 128 + (((4 * ks + quad) ^ n) * 8));
        S[ct] = __builtin_amdgcn_mfma_f32_16x16x32_bf16(qf[ks], kf, S[ct], 0, 0, 0);
      }
    }

    {
      int d0 = tid & 31, k8 = tid >> 5;
#pragma unroll
      for (int p = 0; p < 4; ++p) {
        int d = p * 32 + d0;
        union { short8 v; unsigned short u[8]; } pk;
#pragma unroll
        for (int i = 0; i < 8; ++i) pk.u[i] = Vs[(k8 * 8 + i) * 128 + d];
        *(short8*)(Vt + d * 72 + k8 * 8) = pk.v;
      }
    }
    __syncthreads();

    unsigned short* Ps = Vs;
    const bool diag = (kn == bm);
#pragma unroll
    for (int r = 0; r < 4; ++r) {
      float s0 = S[0][r] * kScale, s1 = S[1][r] * kScale;
      float s2 = S[2][r] * kScale, s3 = S[3][r] * kScale;
      if (diag) {
        int iloc = 16 * w + quad * 4 + r;
        if (n > iloc) s0 = -1e30f;
        if (16 + n > iloc) s1 = -1e30f;
        if (32 + n > iloc) s2 = -1e30f;
        if (48 + n > iloc) s3 = -1e30f;
      }
      float mx = fmaxf(fmaxf(s0, s1), fmaxf(s2, s3));
#pragma unroll
      for (int off = 8; off >= 1; off >>= 1) mx = fmaxf(mx, __shfl_xor(mx, off, 64));
      float mnew = fmaxf(m_i[r], mx);
      float p0 = __expf(s0 - mnew), p1 = __expf(s1 - mnew);
      float p2 = __expf(s2 - mnew), p3 = __expf(s3 - mnew);
      float sum = p0 + p1 + p2 + p3;
#pragma unroll
      for (int off = 8; off >= 1; off >>= 1) sum += __shfl_xor(sum, off, 64);
      float alpha = __expf(m_i[r] - mnew);
      m_i[r] = mnew;
      l_i[r] = l_i[r] * alpha + sum;
#pragma unroll
      for (int dt = 0; dt < 8; ++dt) O[dt][r] *= alpha;
      int prow = 16 * w + quad * 4 + r;
      Ps[prow * 72 + n] = f2bf(p0);
      Ps[prow * 72 + 16 + n] = f2bf(p1);
      Ps[prow * 72 + 32 + n] = f2bf(p2);
      Ps[prow * 72 + 48 + n] = f2bf(p3);
    }
    __syncthreads();

#pragma unroll
    for (int ks = 0; ks < 2; ++ks) {
      short8 pf = *(const short8*)(Ps + (16 * w + n) * 72 + 32 * ks + 8 * quad);
#pragma unroll
      for (int dt = 0; dt < 8; ++dt) {
        short8 vf = *(const short8*)(Vt + (16 * dt + n) * 72 + 32 * ks + 8 * quad);
        O[dt] = __builtin_amdgcn_mfma_f32_16x16x32_bf16(pf, vf, O[dt], 0, 0, 0);
      }
    }
  }

  // epilogue: normalize, gate, store bf16 (feeds out-proj GEMM directly)
#pragma unroll
  for (int r = 0; r < 4; ++r) {
    int row = q0 + 16 * w + quad * 4 + r;
    float inv = 1.0f / l_i[r];
#pragma unroll
    for (int dt = 0; dt < 8; ++dt) {
      int col = 16 * dt + n;
      float g = qkvf[(long)row * kNqkv + 256 * h + 128 + col];
      og[(long)row * kHid + 128 * h + col] = f2bf(O[dt][r] * inv * g);
    }
  }
}

extern "C" void kernel_launch(void* const* d_in, const int* in_sizes, int n_in,
                              void* d_out, int out_size, void* d_ws, size_t ws_size,
                              hipStream_t stream) {
  (void)in_sizes; (void)n_in; (void)out_size; (void)ws_size;
  const float* hs   = (const float*)d_in[0];
  const float* cosb = (const float*)d_in[1];
  const float* sinb = (const float*)d_in[2];
  const float* wqkv = (const float*)d_in[3];
  const float* wo   = (const float*)d_in[4];
  const float* qw   = (const float*)d_in[5];
  const float* kw   = (const float*)d_in[6];
  float* out = (float*)d_out;

  char* ws = (char*)d_ws;
  float* qkv = (float*)ws;                                    // 75.5 MB fp32
  unsigned short* hsb = (unsigned short*)(ws + 75497472);     // 16.8 MB (aliases og)
  unsigned short* og  = hsb;                                  // written after hsb dead
  unsigned short* wt  = (unsigned short*)(ws + 92274688);     // 18.9 MB shared

  cvt_bf16<<<dim3(8192), 256, 0, stream>>>(hs, hsb, (long)kT * kHid);
  transpose_cvt<<<dim3(kNqkv / 32, kHid / 32), 256, 0, stream>>>(wqkv, wt, kHid, kNqkv);
  gemm_bf16<<<dim3(kT / 128, kNqkv / 128), 256, 0, stream>>>(hsb, wt, qkv, kT, kNqkv, kHid);
  norm_rope_cvt<<<dim3(kT * 20), 128, 0, stream>>>(qkv, cosb, sinb, qw, kw);
  transpose_cvt<<<dim3(kHid / 32, kHid / 32), 256, 0, stream>>>(wo, wt, kHid, kHid);
  flash_attn_mfma<<<dim3(kT / 64, kH), 256, 0, stream>>>((const unsigned short*)qkv, qkv, og);
  gemm_bf16<<<dim3(kT / 128, kHid / 128), 256, 0, stream>>>(og, wt, out, kT, kHid, kHid);
}

// Round 5
// 551.698 us; speedup vs baseline: 8.8105x; 1.3294x over previous
//
#include <hip/hip_runtime.h>
#include <hip/hip_bf16.h>
#include <math.h>

// Qwen3.5 attention block, bf16-MFMA everywhere.
// cvt(hs), transpose_cvt(w_qkv) -> gemm_bf16(QKV) -> vt_transpose(V^T global)
// -> norm_rope_cvt -> flash_attn_mfma (no online max, l via ones-MFMA)
// -> transpose_cvt(w_o) -> gemm_bf16(out).

namespace {
constexpr int kT   = 4096;
constexpr int kHid = 2048;
constexpr int kH   = 16;
constexpr int kHkv = 2;
constexpr int kD   = 128;
constexpr int kNqkv = (2 * kH + 2 * kHkv) * kD;  // 4608 floats per row
constexpr int kQsz  = 2 * kH * kD;               // 4096
constexpr int kRowU = kNqkv * 2;                 // 9216 ushorts per row
constexpr float kEps = 1e-6f;
constexpr float kScale = 0.08838834764831845f;   // 128^-0.5
}

typedef __attribute__((ext_vector_type(8))) short short8;
typedef __attribute__((ext_vector_type(4))) float floatx4;

__device__ inline unsigned short f2bf(float x) {
  unsigned u = __float_as_uint(x);
  u = (u + 0x7fffu + ((u >> 16) & 1u)) >> 16;
  return (unsigned short)u;
}

__device__ inline void gload_lds16(const void* g, void* l) {
  typedef const __attribute__((address_space(1))) unsigned GQ;
  typedef __attribute__((address_space(3))) unsigned LQ;
  __builtin_amdgcn_global_load_lds((GQ*)g, (LQ*)l, 16, 0, 0);
}

// ---- fp32 -> bf16 elementwise ----
__global__ __launch_bounds__(256)
void cvt_bf16(const float* __restrict__ in, unsigned short* __restrict__ out,
              long nelem) {
  long i = ((long)blockIdx.x * 256 + threadIdx.x) * 4;
  if (i >= nelem) return;
  float4 v = *(const float4*)(in + i);
  unsigned long long p = (unsigned long long)f2bf(v.x) |
                         ((unsigned long long)f2bf(v.y) << 16) |
                         ((unsigned long long)f2bf(v.z) << 32) |
                         ((unsigned long long)f2bf(v.w) << 48);
  *(unsigned long long*)(out + i) = p;
}

// ---- fp32 [R][C] -> bf16 [C][R] tiled transpose ----
__global__ __launch_bounds__(256)
void transpose_cvt(const float* __restrict__ in, unsigned short* __restrict__ out,
                   int R, int C) {
  __shared__ float t[32][33];
  const int bx = blockIdx.x * 32;
  const int by = blockIdx.y * 32;
  const int x = threadIdx.x & 31, y = threadIdx.x >> 5;
#pragma unroll
  for (int j = 0; j < 4; ++j)
    t[y * 4 + j][x] = in[(long)(by + y * 4 + j) * C + bx + x];
  __syncthreads();
#pragma unroll
  for (int j = 0; j < 4; ++j)
    out[(long)(bx + y * 4 + j) * R + by + x] = f2bf(t[x][y * 4 + j]);
}

// ---- V^T pre-transpose: qkv fp32 V (rows t, 256 cols) -> VtG bf16 [256][T] ----
__global__ __launch_bounds__(256)
void vt_transpose(const float* __restrict__ qkv, unsigned short* __restrict__ VtG) {
  __shared__ float t[32][33];
  const int t0 = blockIdx.x * 32;   // T/32 = 128
  const int c0 = blockIdx.y * 32;   // 256/32 = 8
  const int x = threadIdx.x & 31, y = threadIdx.x >> 5;
#pragma unroll
  for (int j = 0; j < 4; ++j)
    t[y * 4 + j][x] = qkv[(long)(t0 + y * 4 + j) * kNqkv + 4352 + c0 + x];
  __syncthreads();
#pragma unroll
  for (int j = 0; j < 4; ++j)
    VtG[(long)(c0 + y * 4 + j) * kT + t0 + x] = f2bf(t[x][y * 4 + j]);
}

// ---- C[M,N] fp32 = A[M,K]bf16 @ Bt[N,K]bf16^T (unchanged) ----
__global__ __launch_bounds__(256)
void gemm_bf16(const unsigned short* __restrict__ A,
               const unsigned short* __restrict__ Bt, float* __restrict__ C,
               int M, int N, int K) {
  __shared__ __align__(16) unsigned short As[128 * 32];
  __shared__ __align__(16) unsigned short Bs[128 * 32];
  const int tid = threadIdx.x;
  const int lane = tid & 63;
  const int w = tid >> 6;
  const int wr = w >> 1, wc = w & 1;
  const int n = lane & 15;
  const int quad = lane >> 4;
  const long bm = (long)blockIdx.x * 128, bn = (long)blockIdx.y * 128;

  floatx4 acc[4][4];
  floatx4 zero = {0.f, 0.f, 0.f, 0.f};
#pragma unroll
  for (int a = 0; a < 4; ++a)
#pragma unroll
    for (int b = 0; b < 4; ++b) acc[a][b] = zero;

  for (int k0 = 0; k0 < K; k0 += 32) {
    __syncthreads();
#pragma unroll
    for (int it = 0; it < 2; ++it) {
      int ci = (w * 2 + it) * 64 + lane;
      int r = ci >> 2, c = ci & 3;
      int cg = c ^ ((r >> 1) & 3);
      gload_lds16(A + (bm + r) * (long)K + k0 + cg * 8, As + (w * 2 + it) * 512);
      gload_lds16(Bt + (bn + r) * (long)K + k0 + cg * 8, Bs + (w * 2 + it) * 512);
    }
    __syncthreads();

    short8 af[4], bf[4];
#pragma unroll
    for (int a = 0; a < 4; ++a) {
      int m = wr * 64 + a * 16 + n;
      af[a] = *(const short8*)(As + m * 32 + (quad ^ ((m >> 1) & 3)) * 8);
    }
#pragma unroll
    for (int b = 0; b < 4; ++b) {
      int nn = wc * 64 + b * 16 + n;
      bf[b] = *(const short8*)(Bs + nn * 32 + (quad ^ ((nn >> 1) & 3)) * 8);
    }
#pragma unroll
    for (int a = 0; a < 4; ++a)
#pragma unroll
      for (int b = 0; b < 4; ++b)
        acc[a][b] = __builtin_amdgcn_mfma_f32_16x16x32_bf16(af[a], bf[b], acc[a][b], 0, 0, 0);
  }
#pragma unroll
  for (int a = 0; a < 4; ++a)
#pragma unroll
    for (int b = 0; b < 4; ++b)
#pragma unroll
      for (int r = 0; r < 4; ++r)
        C[(bm + wr * 64 + a * 16 + quad * 4 + r) * (long)N + bn + wc * 64 + b * 16 + n] =
            acc[a][b][r];
}

// ------------- RMSNorm + RoPE + bf16 pack (q,k only; v handled by vt_transpose) ---
__global__ __launch_bounds__(128)
void norm_rope_cvt(float* qkv, const float* __restrict__ cosb,
                   const float* __restrict__ sinb, const float* __restrict__ qw,
                   const float* __restrict__ kw) {
  unsigned short* qkvu = (unsigned short*)qkv;
  const int blk = blockIdx.x;
  const int t = blk / 18;
  const int h = blk % 18;
  const int i = threadIdx.x;

  const bool isq = (h < kH);
  const long base = (long)t * kNqkv + (isq ? h * 2 * kD : kQsz + (h - kH) * kD);
  float x = qkv[base + i];
  float v = x * x;
#pragma unroll
  for (int off = 1; off < 64; off <<= 1) v += __shfl_xor(v, off, 64);
  __shared__ float wsum[2];
  if ((i & 63) == 0) wsum[i >> 6] = v;
  __syncthreads();
  float rms = rsqrtf((wsum[0] + wsum[1]) * (1.0f / kD) + kEps);
  float nv = x * rms * (isq ? qw[i] : kw[i]);
  __shared__ float nb[128];
  nb[i] = nv;
  __syncthreads();
  float rot = (i < 64) ? -nb[i + 64] : nb[i - 64];
  float ro = nv * cosb[t * kD + i] + rot * sinb[t * kD + i];
  if (isq) {
    float g = qkv[base + kD + i];
    qkv[base + kD + i] = 1.0f / (1.0f + __expf(-g));
    qkvu[(long)t * kRowU + 512 * h + i] = f2bf(ro);
  } else {
    qkvu[(long)t * kRowU + 8192 + 256 * (h - kH) + i] = f2bf(ro);
  }
}

// ---------------- bf16 MFMA flash attention v2 ----------------
// No online max (|s*scale| <= 11.31 by RMSNorm), l via ones-column MFMA.
// Ks 16KB + Vt 16KB = 32KB LDS -> 4 blocks/CU; Ps aliases Ks (row-swizzled).
__global__ __launch_bounds__(256, 4)
void flash_attn_mfma(const unsigned short* qkvu, const float* qkvf,
                     const unsigned short* VtG, unsigned short* __restrict__ og) {
  __shared__ __align__(16) unsigned short Ks[64 * 128];  // K tile; Ps aliases
  __shared__ __align__(16) unsigned short Vt[128 * 64];  // V^T tile (swizzled)

  const int tid = threadIdx.x;
  const int lane = tid & 63;
  const int w = tid >> 6;
  const int n = lane & 15;
  const int quad = lane >> 4;
  // bm fast-varying, alternating small/large for per-CU balance
  const int g = blockIdx.x;
  const int m = g & 63;
  const int bm = (m & 1) ? 63 - (m >> 1) : (m >> 1);
  const int h = g >> 6;
  const int hk = h >> 3;
  const int q0 = bm * 64;

  short8 qf[4];
  {
    const unsigned short* qrow = qkvu + (long)(q0 + 16 * w + n) * kRowU + 512 * h;
#pragma unroll
    for (int ks = 0; ks < 4; ++ks)
      qf[ks] = *(const short8*)(qrow + 32 * ks + 8 * quad);
  }
  short8 lfrag;  // B-frag: col 0 = ones -> row-sum accumulator
  {
    short o = (n == 0) ? (short)0x3F80 : (short)0;
    lfrag = (short8){o, o, o, o, o, o, o, o};
  }

  floatx4 O[8];
  floatx4 zero = {0.f, 0.f, 0.f, 0.f};
#pragma unroll
  for (int dt = 0; dt < 8; ++dt) O[dt] = zero;
  floatx4 Ol = zero;

  for (int kn = 0; kn <= bm; ++kn) {
    __syncthreads();  // (1) prev PV reads done before restage
    // stage K: 64 rows x 128 d, global-side chunk swizzle c ^ (r&15)
#pragma unroll
    for (int it = 0; it < 4; ++it) {
      int pc = (w * 4 + it) * 64 + lane;
      int r = pc >> 4, c = pc & 15;
      int lc = c ^ (r & 15);
      gload_lds16(qkvu + (long)(kn * 64 + r) * kRowU + 8192 + 256 * hk + 8 * lc,
                  Ks + (w * 4 + it) * 512);
    }
    // stage V^T: 128 rows (d) x 64 keys = 1024 chunks -> 4 iterations
#pragma unroll
    for (int it = 0; it < 4; ++it) {
      int pc = (w * 4 + it) * 64 + lane;
      int d = pc >> 3, c = pc & 7;
      int lc = c ^ (d & 7);
      gload_lds16(VtG + (long)hk * (128 * kT) + (long)d * kT + kn * 64 + 8 * lc,
                  Vt + (w * 4 + it) * 512);
    }
    __syncthreads();  // (2) staging complete

    // S = Q K^T
    floatx4 S[4];
#pragma unroll
    for (int ct = 0; ct < 4; ++ct) S[ct] = zero;
#pragma unroll
    for (int ks = 0; ks < 4; ++ks) {
#pragma unroll
      for (int ct = 0; ct < 4; ++ct) {
        int row = 16 * ct + n;
        short8 kf = *(const short8*)(Ks + row * 128 + ((4 * ks + quad) ^ n) * 8);
        S[ct] = __builtin_amdgcn_mfma_f32_16x16x32_bf16(qf[ks], kf, S[ct], 0, 0, 0);
      }
    }
    __syncthreads();  // (3) all QK reads done before Ps overwrites Ks

    // p = exp(s*scale), fixed max=0; write Ps (aliases Ks, row-swizzled chunks)
    unsigned short* Ps = Ks;
    const bool diag = (kn == bm);
    const int hi = n >> 3, lo = n & 7;
#pragma unroll
    for (int r = 0; r < 4; ++r) {
      int iloc = 16 * w + quad * 4 + r;
      float p0 = __expf(S[0][r] * kScale);
      float p1 = __expf(S[1][r] * kScale);
      float p2 = __expf(S[2][r] * kScale);
      float p3 = __expf(S[3][r] * kScale);
      if (diag) {
        if (n > iloc) p0 = 0.f;
        if (16 + n > iloc) p1 = 0.f;
        if (32 + n > iloc) p2 = 0.f;
        if (48 + n > iloc) p3 = 0.f;
      }
      int prow = 16 * w + quad * 4 + r;
      int sw = prow & 7;
      Ps[prow * 128 + (((0 + hi) ^ sw) << 3) + lo] = f2bf(p0);
      Ps[prow * 128 + (((2 + hi) ^ sw) << 3) + lo] = f2bf(p1);
      Ps[prow * 128 + (((4 + hi) ^ sw) << 3) + lo] = f2bf(p2);
      Ps[prow * 128 + (((6 + hi) ^ sw) << 3) + lo] = f2bf(p3);
    }
    __asm__ volatile("s_waitcnt lgkmcnt(0)" ::: "memory");  // own-wave Ps visible

    // O += P V ; Ol += P @ ones (A-frag reads own wave's rows only)
#pragma unroll
    for (int ks = 0; ks < 2; ++ks) {
      int rr = 16 * w + n;
      short8 pf = *(const short8*)(Ps + rr * 128 + (((4 * ks + quad) ^ (rr & 7)) << 3));
      Ol = __builtin_amdgcn_mfma_f32_16x16x32_bf16(pf, lfrag, Ol, 0, 0, 0);
#pragma unroll
      for (int dt = 0; dt < 8; ++dt) {
        int d = 16 * dt + n;
        short8 vf = *(const short8*)(Vt + d * 64 + (((4 * ks + quad) ^ (d & 7)) << 3));
        O[dt] = __builtin_amdgcn_mfma_f32_16x16x32_bf16(pf, vf, O[dt], 0, 0, 0);
      }
    }
  }

  // epilogue: l broadcast (lane n=0 of each quad), normalize, gate, store bf16
#pragma unroll
  for (int r = 0; r < 4; ++r) {
    float l = __shfl(Ol[r], quad << 4, 64);
    float inv = 1.0f / l;
    int row = q0 + 16 * w + quad * 4 + r;
#pragma unroll
    for (int dt = 0; dt < 8; ++dt) {
      int col = 16 * dt + n;
      float gte = qkvf[(long)row * kNqkv + 256 * h + 128 + col];
      og[(long)row * kHid + 128 * h + col] = f2bf(O[dt][r] * inv * gte);
    }
  }
}

extern "C" void kernel_launch(void* const* d_in, const int* in_sizes, int n_in,
                              void* d_out, int out_size, void* d_ws, size_t ws_size,
                              hipStream_t stream) {
  (void)in_sizes; (void)n_in; (void)out_size; (void)ws_size;
  const float* hs   = (const float*)d_in[0];
  const float* cosb = (const float*)d_in[1];
  const float* sinb = (const float*)d_in[2];
  const float* wqkv = (const float*)d_in[3];
  const float* wo   = (const float*)d_in[4];
  const float* qw   = (const float*)d_in[5];
  const float* kw   = (const float*)d_in[6];
  float* out = (float*)d_out;

  char* ws = (char*)d_ws;
  float* qkv = (float*)ws;                                    // 75.5 MB fp32
  unsigned short* hsb = (unsigned short*)(ws + 75497472);     // 16.8 MB (aliases og)
  unsigned short* og  = hsb;                                  // written after hsb dead
  unsigned short* wt  = (unsigned short*)(ws + 92274688);     // 18.9 MB shared
  unsigned short* VtG = wt;  // aliases dead w_qkv^T during flash (w_o^T written after)

  cvt_bf16<<<dim3(8192), 256, 0, stream>>>(hs, hsb, (long)kT * kHid);
  transpose_cvt<<<dim3(kNqkv / 32, kHid / 32), 256, 0, stream>>>(wqkv, wt, kHid, kNqkv);
  gemm_bf16<<<dim3(kT / 128, kNqkv / 128), 256, 0, stream>>>(hsb, wt, qkv, kT, kNqkv, kHid);
  vt_transpose<<<dim3(kT / 32, 8), 256, 0, stream>>>(qkv, VtG);
  norm_rope_cvt<<<dim3(kT * 18), 128, 0, stream>>>(qkv, cosb, sinb, qw, kw);
  flash_attn_mfma<<<dim3(kT / 64 * kH), 256, 0, stream>>>((const unsigned short*)qkv, qkv, VtG, og);
  transpose_cvt<<<dim3(kHid / 32, kHid / 32), 256, 0, stream>>>(wo, wt, kHid, kHid);
  gemm_bf16<<<dim3(kT / 128, kHid / 128), 256, 0, stream>>>(og, wt, out, kT, kHid, kHid);
}

// Round 6
// 504.569 us; speedup vs baseline: 9.6334x; 1.0934x over previous
//
#include <hip/hip_runtime.h>
#include <hip/hip_bf16.h>
#include <math.h>

// Qwen3.5 attention block, bf16-MFMA everywhere.
// cvt(hs), transpose_cvt(w_qkv) -> gemm_bf16(QKV, BK=64) -> vt_transpose ->
// norm_rope_cvt -> flash_attn_mfma v3 (BM=128, heavy-first) ->
// transpose_cvt(w_o) -> gemm_bf16(out).

namespace {
constexpr int kT   = 4096;
constexpr int kHid = 2048;
constexpr int kH   = 16;
constexpr int kHkv = 2;
constexpr int kD   = 128;
constexpr int kNqkv = (2 * kH + 2 * kHkv) * kD;  // 4608 floats per row
constexpr int kQsz  = 2 * kH * kD;               // 4096
constexpr int kRowU = kNqkv * 2;                 // 9216 ushorts per row
constexpr float kEps = 1e-6f;
constexpr float kScale = 0.08838834764831845f;   // 128^-0.5
}

typedef __attribute__((ext_vector_type(8))) short short8;
typedef __attribute__((ext_vector_type(4))) float floatx4;

__device__ inline unsigned short f2bf(float x) {
  unsigned u = __float_as_uint(x);
  u = (u + 0x7fffu + ((u >> 16) & 1u)) >> 16;
  return (unsigned short)u;
}

__device__ inline void gload_lds16(const void* g, void* l) {
  typedef const __attribute__((address_space(1))) unsigned GQ;
  typedef __attribute__((address_space(3))) unsigned LQ;
  __builtin_amdgcn_global_load_lds((GQ*)g, (LQ*)l, 16, 0, 0);
}

// ---- fp32 -> bf16 elementwise ----
__global__ __launch_bounds__(256)
void cvt_bf16(const float* __restrict__ in, unsigned short* __restrict__ out,
              long nelem) {
  long i = ((long)blockIdx.x * 256 + threadIdx.x) * 4;
  if (i >= nelem) return;
  float4 v = *(const float4*)(in + i);
  unsigned long long p = (unsigned long long)f2bf(v.x) |
                         ((unsigned long long)f2bf(v.y) << 16) |
                         ((unsigned long long)f2bf(v.z) << 32) |
                         ((unsigned long long)f2bf(v.w) << 48);
  *(unsigned long long*)(out + i) = p;
}

// ---- fp32 [R][C] -> bf16 [C][R] tiled transpose ----
__global__ __launch_bounds__(256)
void transpose_cvt(const float* __restrict__ in, unsigned short* __restrict__ out,
                   int R, int C) {
  __shared__ float t[32][33];
  const int bx = blockIdx.x * 32;
  const int by = blockIdx.y * 32;
  const int x = threadIdx.x & 31, y = threadIdx.x >> 5;
#pragma unroll
  for (int j = 0; j < 4; ++j)
    t[y * 4 + j][x] = in[(long)(by + y * 4 + j) * C + bx + x];
  __syncthreads();
#pragma unroll
  for (int j = 0; j < 4; ++j)
    out[(long)(bx + y * 4 + j) * R + by + x] = f2bf(t[x][y * 4 + j]);
}

// ---- V^T pre-transpose: qkv fp32 V (rows t, 256 cols) -> VtG bf16 [256][T] ----
__global__ __launch_bounds__(256)
void vt_transpose(const float* __restrict__ qkv, unsigned short* __restrict__ VtG) {
  __shared__ float t[32][33];
  const int t0 = blockIdx.x * 32;
  const int c0 = blockIdx.y * 32;
  const int x = threadIdx.x & 31, y = threadIdx.x >> 5;
#pragma unroll
  for (int j = 0; j < 4; ++j)
    t[y * 4 + j][x] = qkv[(long)(t0 + y * 4 + j) * kNqkv + 4352 + c0 + x];
  __syncthreads();
#pragma unroll
  for (int j = 0; j < 4; ++j)
    VtG[(long)(c0 + y * 4 + j) * kT + t0 + x] = f2bf(t[x][y * 4 + j]);
}

// ---- C[M,N] fp32 = A[M,K]bf16 @ Bt[N,K]bf16^T. 128x128 tile, BK=64. ----
__global__ __launch_bounds__(256)
void gemm_bf16(const unsigned short* __restrict__ A,
               const unsigned short* __restrict__ Bt, float* __restrict__ C,
               int M, int N, int K) {
  __shared__ __align__(16) unsigned short As[128 * 64];
  __shared__ __align__(16) unsigned short Bs[128 * 64];
  const int tid = threadIdx.x;
  const int lane = tid & 63;
  const int w = tid >> 6;
  const int wr = w >> 1, wc = w & 1;
  const int n = lane & 15;
  const int quad = lane >> 4;
  const long bm = (long)blockIdx.x * 128, bn = (long)blockIdx.y * 128;

  floatx4 acc[4][4];
  floatx4 zero = {0.f, 0.f, 0.f, 0.f};
#pragma unroll
  for (int a = 0; a < 4; ++a)
#pragma unroll
    for (int b = 0; b < 4; ++b) acc[a][b] = zero;

  for (int k0 = 0; k0 < K; k0 += 64) {
    __syncthreads();
#pragma unroll
    for (int it = 0; it < 4; ++it) {
      int ci = it * 256 + tid;            // 16B chunk id 0..1023
      int r = ci >> 3, c = ci & 7;
      int cg = c ^ (r & 7);               // global chunk for this slot
      gload_lds16(A + (bm + r) * (long)K + k0 + cg * 8, As + (it * 256 + w * 64) * 8);
      gload_lds16(Bt + (bn + r) * (long)K + k0 + cg * 8, Bs + (it * 256 + w * 64) * 8);
    }
    __syncthreads();

#pragma unroll
    for (int ks = 0; ks < 2; ++ks) {
      short8 af[4], bf[4];
#pragma unroll
      for (int a = 0; a < 4; ++a) {
        int m = wr * 64 + a * 16 + n;
        af[a] = *(const short8*)(As + m * 64 + ((4 * ks + quad) ^ (m & 7)) * 8);
      }
#pragma unroll
      for (int b = 0; b < 4; ++b) {
        int nn = wc * 64 + b * 16 + n;
        bf[b] = *(const short8*)(Bs + nn * 64 + ((4 * ks + quad) ^ (nn & 7)) * 8);
      }
#pragma unroll
      for (int a = 0; a < 4; ++a)
#pragma unroll
        for (int b = 0; b < 4; ++b)
          acc[a][b] = __builtin_amdgcn_mfma_f32_16x16x32_bf16(af[a], bf[b], acc[a][b], 0, 0, 0);
    }
  }
#pragma unroll
  for (int a = 0; a < 4; ++a)
#pragma unroll
    for (int b = 0; b < 4; ++b)
#pragma unroll
      for (int r = 0; r < 4; ++r)
        C[(bm + wr * 64 + a * 16 + quad * 4 + r) * (long)N + bn + wc * 64 + b * 16 + n] =
            acc[a][b][r];
}

// ------------- RMSNorm + RoPE + bf16 pack (q,k only) -------------
__global__ __launch_bounds__(128)
void norm_rope_cvt(float* qkv, const float* __restrict__ cosb,
                   const float* __restrict__ sinb, const float* __restrict__ qw,
                   const float* __restrict__ kw) {
  unsigned short* qkvu = (unsigned short*)qkv;
  const int blk = blockIdx.x;
  const int t = blk / 18;
  const int h = blk % 18;
  const int i = threadIdx.x;

  const bool isq = (h < kH);
  const long base = (long)t * kNqkv + (isq ? h * 2 * kD : kQsz + (h - kH) * kD);
  float x = qkv[base + i];
  float v = x * x;
#pragma unroll
  for (int off = 1; off < 64; off <<= 1) v += __shfl_xor(v, off, 64);
  __shared__ float wsum[2];
  if ((i & 63) == 0) wsum[i >> 6] = v;
  __syncthreads();
  float rms = rsqrtf((wsum[0] + wsum[1]) * (1.0f / kD) + kEps);
  float nv = x * rms * (isq ? qw[i] : kw[i]);
  __shared__ float nb[128];
  nb[i] = nv;
  __syncthreads();
  float rot = (i < 64) ? -nb[i + 64] : nb[i - 64];
  float ro = nv * cosb[t * kD + i] + rot * sinb[t * kD + i];
  if (isq) {
    float g = qkv[base + kD + i];
    qkv[base + kD + i] = 1.0f / (1.0f + __expf(-g));
    qkvu[(long)t * kRowU + 512 * h + i] = f2bf(ro);
  } else {
    qkvu[(long)t * kRowU + 8192 + 256 * (h - kH) + i] = f2bf(ro);
  }
}

// ---------------- bf16 MFMA flash attention v3 ----------------
// BM=128 q rows/block (wave owns 32 rows = 2 m-tiles -> K/V frag reads shared),
// BN=64 keys/tile. No online max; l via ones-column MFMA. Ps aliases Ks.
// Heavy blocks dispatched first for LPT balance.
__global__ __launch_bounds__(256)
void flash_attn_mfma(const unsigned short* qkvu, const float* qkvf,
                     const unsigned short* VtG, unsigned short* __restrict__ og) {
  __shared__ __align__(16) unsigned short Ks[64 * 128];  // K tile; Ps aliases (128x64)
  __shared__ __align__(16) unsigned short Vt[128 * 64];  // V^T tile (swizzled)

  const int tid = threadIdx.x;
  const int lane = tid & 63;
  const int w = tid >> 6;
  const int n = lane & 15;
  const int quad = lane >> 4;
  const int g = blockIdx.x;
  const int h = g & 15;
  const int bm = 31 - (g >> 4);   // heavy-first
  const int hk = h >> 3;
  const int q0 = bm * 128;

  short8 qf[2][4];
#pragma unroll
  for (int mt = 0; mt < 2; ++mt) {
    const unsigned short* qrow =
        qkvu + (long)(q0 + 32 * w + 16 * mt + n) * kRowU + 512 * h;
#pragma unroll
    for (int ks = 0; ks < 4; ++ks)
      qf[mt][ks] = *(const short8*)(qrow + 32 * ks + 8 * quad);
  }
  short8 lfrag;  // B-frag: col 0 = ones -> row-sum accumulator
  {
    short o = (n == 0) ? (short)0x3F80 : (short)0;
    lfrag = (short8){o, o, o, o, o, o, o, o};
  }

  floatx4 O[2][8];
  floatx4 Ol[2];
  floatx4 zero = {0.f, 0.f, 0.f, 0.f};
#pragma unroll
  for (int mt = 0; mt < 2; ++mt) {
    Ol[mt] = zero;
#pragma unroll
    for (int dt = 0; dt < 8; ++dt) O[mt][dt] = zero;
  }

  const int kn_end = 2 * bm + 1;
  for (int kn = 0; kn <= kn_end; ++kn) {
    __syncthreads();  // (1) prev PV reads done before restage
    // stage K: 64 rows x 128 d, chunk swizzle c ^ (r&15)
#pragma unroll
    for (int it = 0; it < 4; ++it) {
      int pc = (w * 4 + it) * 64 + lane;
      int r = pc >> 4, c = pc & 15;
      int lc = c ^ (r & 15);
      gload_lds16(qkvu + (long)(kn * 64 + r) * kRowU + 8192 + 256 * hk + 8 * lc,
                  Ks + (w * 4 + it) * 512);
    }
    // stage V^T: 128 rows (d) x 64 keys, chunk swizzle c ^ (d&7)
#pragma unroll
    for (int it = 0; it < 4; ++it) {
      int pc = (w * 4 + it) * 64 + lane;
      int d = pc >> 3, c = pc & 7;
      int lc = c ^ (d & 7);
      gload_lds16(VtG + (long)hk * (128 * kT) + (long)d * kT + kn * 64 + 8 * lc,
                  Vt + (w * 4 + it) * 512);
    }
    __syncthreads();  // (2) staging complete

    // S = Q K^T  (kf shared across both m-tiles)
    floatx4 S[2][4];
#pragma unroll
    for (int mt = 0; mt < 2; ++mt)
#pragma unroll
      for (int ct = 0; ct < 4; ++ct) S[mt][ct] = zero;
#pragma unroll
    for (int ks = 0; ks < 4; ++ks) {
#pragma unroll
      for (int ct = 0; ct < 4; ++ct) {
        int row = 16 * ct + n;
        short8 kf = *(const short8*)(Ks + row * 128 + ((4 * ks + quad) ^ n) * 8);
        S[0][ct] = __builtin_amdgcn_mfma_f32_16x16x32_bf16(qf[0][ks], kf, S[0][ct], 0, 0, 0);
        S[1][ct] = __builtin_amdgcn_mfma_f32_16x16x32_bf16(qf[1][ks], kf, S[1][ct], 0, 0, 0);
      }
    }
    __syncthreads();  // (3) all QK reads done before Ps overwrites Ks

    // p = exp(s*scale); write Ps (aliases Ks; 128 rows x 64 cols, row-swizzled)
    unsigned short* Ps = Ks;
    const bool needmask = (kn >= 2 * bm);
    const int jbase = (kn - 2 * bm) * 64;
    const int hi = n >> 3, lo = n & 7;
#pragma unroll
    for (int mt = 0; mt < 2; ++mt) {
#pragma unroll
      for (int r = 0; r < 4; ++r) {
        int prow = 32 * w + 16 * mt + quad * 4 + r;
        float p0 = __expf(S[mt][0][r] * kScale);
        float p1 = __expf(S[mt][1][r] * kScale);
        float p2 = __expf(S[mt][2][r] * kScale);
        float p3 = __expf(S[mt][3][r] * kScale);
        if (needmask) {
          if (jbase + n > prow) p0 = 0.f;
          if (jbase + 16 + n > prow) p1 = 0.f;
          if (jbase + 32 + n > prow) p2 = 0.f;
          if (jbase + 48 + n > prow) p3 = 0.f;
        }
        int sw = prow & 7;
        Ps[prow * 64 + (((0 + hi) ^ sw) << 3) + lo] = f2bf(p0);
        Ps[prow * 64 + (((2 + hi) ^ sw) << 3) + lo] = f2bf(p1);
        Ps[prow * 64 + (((4 + hi) ^ sw) << 3) + lo] = f2bf(p2);
        Ps[prow * 64 + (((6 + hi) ^ sw) << 3) + lo] = f2bf(p3);
      }
    }
    __asm__ volatile("s_waitcnt lgkmcnt(0)" ::: "memory");  // own-wave Ps visible

    // O += P V ; Ol += P @ ones  (vf shared across both m-tiles)
#pragma unroll
    for (int ks = 0; ks < 2; ++ks) {
      int r0 = 32 * w + n, r1 = 32 * w + 16 + n;
      short8 pf0 = *(const short8*)(Ps + r0 * 64 + (((4 * ks + quad) ^ (r0 & 7)) << 3));
      short8 pf1 = *(const short8*)(Ps + r1 * 64 + (((4 * ks + quad) ^ (r1 & 7)) << 3));
      Ol[0] = __builtin_amdgcn_mfma_f32_16x16x32_bf16(pf0, lfrag, Ol[0], 0, 0, 0);
      Ol[1] = __builtin_amdgcn_mfma_f32_16x16x32_bf16(pf1, lfrag, Ol[1], 0, 0, 0);
#pragma unroll
      for (int dt = 0; dt < 8; ++dt) {
        int d = 16 * dt + n;
        short8 vf = *(const short8*)(Vt + d * 64 + (((4 * ks + quad) ^ (d & 7)) << 3));
        O[0][dt] = __builtin_amdgcn_mfma_f32_16x16x32_bf16(pf0, vf, O[0][dt], 0, 0, 0);
        O[1][dt] = __builtin_amdgcn_mfma_f32_16x16x32_bf16(pf1, vf, O[1][dt], 0, 0, 0);
      }
    }
  }

  // epilogue: l broadcast, normalize, gate, store bf16
#pragma unroll
  for (int mt = 0; mt < 2; ++mt) {
#pragma unroll
    for (int r = 0; r < 4; ++r) {
      float l = __shfl(Ol[mt][r], quad << 4, 64);
      float inv = 1.0f / l;
      int row = q0 + 32 * w + 16 * mt + quad * 4 + r;
#pragma unroll
      for (int dt = 0; dt < 8; ++dt) {
        int col = 16 * dt + n;
        float gte = qkvf[(long)row * kNqkv + 256 * h + 128 + col];
        og[(long)row * kHid + 128 * h + col] = f2bf(O[mt][dt][r] * inv * gte);
      }
    }
  }
}

extern "C" void kernel_launch(void* const* d_in, const int* in_sizes, int n_in,
                              void* d_out, int out_size, void* d_ws, size_t ws_size,
                              hipStream_t stream) {
  (void)in_sizes; (void)n_in; (void)out_size; (void)ws_size;
  const float* hs   = (const float*)d_in[0];
  const float* cosb = (const float*)d_in[1];
  const float* sinb = (const float*)d_in[2];
  const float* wqkv = (const float*)d_in[3];
  const float* wo   = (const float*)d_in[4];
  const float* qw   = (const float*)d_in[5];
  const float* kw   = (const float*)d_in[6];
  float* out = (float*)d_out;

  char* ws = (char*)d_ws;
  float* qkv = (float*)ws;                                    // 75.5 MB fp32
  unsigned short* hsb = (unsigned short*)(ws + 75497472);     // 16.8 MB (aliases og)
  unsigned short* og  = hsb;                                  // written after hsb dead
  unsigned short* wt  = (unsigned short*)(ws + 92274688);     // 18.9 MB shared
  unsigned short* VtG = wt;  // aliases dead w_qkv^T during flash (w_o^T written after)

  cvt_bf16<<<dim3(8192), 256, 0, stream>>>(hs, hsb, (long)kT * kHid);
  transpose_cvt<<<dim3(kNqkv / 32, kHid / 32), 256, 0, stream>>>(wqkv, wt, kHid, kNqkv);
  gemm_bf16<<<dim3(kT / 128, kNqkv / 128), 256, 0, stream>>>(hsb, wt, qkv, kT, kNqkv, kHid);
  vt_transpose<<<dim3(kT / 32, 8), 256, 0, stream>>>(qkv, VtG);
  norm_rope_cvt<<<dim3(kT * 18), 128, 0, stream>>>(qkv, cosb, sinb, qw, kw);
  flash_attn_mfma<<<dim3(kT / 128 * kH), 256, 0, stream>>>((const unsigned short*)qkv, qkv, VtG, og);
  transpose_cvt<<<dim3(kHid / 32, kHid / 32), 256, 0, stream>>>(wo, wt, kHid, kHid);
  gemm_bf16<<<dim3(kT / 128, kHid / 128), 256, 0, stream>>>(og, wt, out, kT, kHid, kHid);
}